// Round 10
// baseline (291.180 us; speedup 1.0000x reference)
//
#include <hip/hip_runtime.h>

typedef _Float16 f16x8 __attribute__((ext_vector_type(8)));
typedef float f32x16 __attribute__((ext_vector_type(16)));

constexpr int D = 128;
constexpr int K = 256;
constexpr float LR = 0.01f;
constexpr float LO_SCALE = 4096.0f;
constexpr float LO_INV = 1.0f / 4096.0f;

// ---------------- zero ws ----------------
__global__ __launch_bounds__(256) void k_zero(float* p, int n) {
  int i = blockIdx.x * 256 + threadIdx.x;
  if (i < n) p[i] = 0.0f;
}

__global__ __launch_bounds__(256) void k_init_best(unsigned long long* b) {
  b[blockIdx.x * 256 + threadIdx.x] = ~0ull;
}

// ---------------- prep: split centroids (prescaled by -2) + cnorm extension ---------
__global__ __launch_bounds__(128) void k_prep(const float* __restrict__ cent,
                                              _Float16* __restrict__ csplit,
                                              _Float16* __restrict__ extH,
                                              _Float16* __restrict__ extL, int mode) {
  int c = blockIdx.x, k = threadIdx.x;
  float x = cent[c * D + k];
  float ca = -2.0f * x;
  _Float16 h = (_Float16)ca;
  float r = ca - (float)h;
  _Float16 lo = (_Float16)(r * LO_SCALE);
  if (mode == 1) {
    int cc = c & 127;
    int base = (c >> 7) * 32768;
    int sw = (cc * 128 + k) ^ ((cc & 15) << 3);
    csplit[base + sw] = h;
    csplit[base + 16384 + sw] = lo;
  } else {
    int sw = (c * 128 + k) ^ ((c & 15) << 3);
    csplit[sw] = h;
    csplit[32768 + sw] = lo;
  }

  float s = x * x;
#pragma unroll
  for (int off = 32; off; off >>= 1) s += __shfl_down(s, off, 64);
  __shared__ float w0;
  if (k == 0) w0 = s;
  __syncthreads();
  if (k == 64) {
    float cn = w0 + s;
    _Float16 c1 = (_Float16)cn;
    float rr = cn - (float)c1;
    _Float16 c2s = (_Float16)(rr * LO_SCALE);
    float rr2 = rr - (float)c2s * LO_INV;
    _Float16 c3s = (_Float16)(rr2 * LO_SCALE);
    extH[c * 8 + 0] = c1;
    extL[c * 8 + 0] = c2s;
    extL[c * 8 + 1] = c3s;
  }
  if (k >= 1 && k < 8) extH[c * 8 + k] = (_Float16)0.0f;
  if (k >= 2 && k < 8) extL[c * 8 + k] = (_Float16)0.0f;
}

// ---------------- assignment v3: cluster-split, 1024-thr blocks, 32 waves/CU ------
// bid&1 = cluster half (128 clusters in 68.5 KB LDS); 16 waves/block, 2 blocks/CU
// -> 32 waves/CU. Per iteration t the block covers 512 points (wave wv: 32 pts).
__global__ __launch_bounds__(1024, 8) void k_assign2(
    const float* __restrict__ keys, const _Float16* __restrict__ csplit,
    const _Float16* __restrict__ extH, const _Float16* __restrict__ extL,
    unsigned long long* __restrict__ best, int T) {
  __shared__ __align__(16) _Float16 csH[16384];  // 32 KB
  __shared__ __align__(16) _Float16 csL[16384];  // 32 KB
  __shared__ __align__(16) _Float16 exh[1032], exl[1032];

  const int tid = threadIdx.x;
  const int lane = tid & 63;
  const int wv = tid >> 6;           // 0..15
  const int col = lane & 31;
  const int hl = lane >> 5;
  const int half = blockIdx.x & 1;
  const size_t base_pt = (size_t)(blockIdx.x >> 1) * 512 * T;

  // stage 68.5 KB (L2/L3-hot), 1024 threads
  {
    const float4* sH = reinterpret_cast<const float4*>(csplit + half * 32768);
    const float4* sL = reinterpret_cast<const float4*>(csplit + half * 32768 + 16384);
    float4* dH = reinterpret_cast<float4*>(csH);
    float4* dL = reinterpret_cast<float4*>(csL);
#pragma unroll
    for (int it = 0; it < 2; ++it) {
      dH[tid + 1024 * it] = sH[tid + 1024 * it];
      dL[tid + 1024 * it] = sL[tid + 1024 * it];
    }
    if (tid < 128)
      reinterpret_cast<float4*>(exh)[tid] =
          reinterpret_cast<const float4*>(extH + half * 1024)[tid];
    else if (tid < 256)
      reinterpret_cast<float4*>(exl)[tid - 128] =
          reinterpret_cast<const float4*>(extL + half * 1024)[tid - 128];
    if (tid < 8) { exh[1024 + tid] = (_Float16)0.0f; exl[1024 + tid] = (_Float16)0.0f; }
  }

  f16x8 beh = {};
  if (hl == 0) { beh[0] = (_Float16)1.0f; beh[1] = (_Float16)1.0f; }
  __syncthreads();

#pragma unroll 1
  for (int t = 0; t < T; ++t) {
    const size_t pt = base_pt + (size_t)t * 512 + wv * 32 + col;
    f16x8 bh[8], bl[8];
    {
      const float* kp = keys + pt * D + hl * 8;
#pragma unroll
      for (int kt = 0; kt < 8; ++kt) {
        float4 x0 = *reinterpret_cast<const float4*>(kp + kt * 16);
        float4 x1 = *reinterpret_cast<const float4*>(kp + kt * 16 + 4);
        float xs[8] = {x0.x, x0.y, x0.z, x0.w, x1.x, x1.y, x1.z, x1.w};
#pragma unroll
        for (int j = 0; j < 8; ++j) {
          float x = xs[j];
          _Float16 h = (_Float16)x;
          bh[kt][j] = h;
          bl[kt][j] = (_Float16)((x - (float)h) * LO_SCALE);
        }
      }
    }

    float bestd = 3.0e38f;
    int bestc = 0;
#pragma unroll 1
    for (int mt = 0; mt < 4; ++mt) {
      f32x16 acc, acc2;
#pragma unroll
      for (int r = 0; r < 16; ++r) { acc[r] = 0.0f; acc2[r] = 0.0f; }
      const int cc = mt * 32 + col;
#pragma unroll
      for (int kt = 0; kt < 8; ++kt) {
        int sw = (cc * 128 + kt * 16 + hl * 8) ^ ((cc & 15) << 3);
        f16x8 ah = *reinterpret_cast<const f16x8*>(&csH[sw]);
        f16x8 al = *reinterpret_cast<const f16x8*>(&csL[sw]);
        acc = __builtin_amdgcn_mfma_f32_32x32x16_f16(ah, bh[kt], acc, 0, 0, 0);
        acc2 = __builtin_amdgcn_mfma_f32_32x32x16_f16(ah, bl[kt], acc2, 0, 0, 0);
        acc2 = __builtin_amdgcn_mfma_f32_32x32x16_f16(al, bh[kt], acc2, 0, 0, 0);
      }
      {
        int off = hl ? 1024 : cc * 8;
        f16x8 aeh = *reinterpret_cast<const f16x8*>(&exh[off]);
        f16x8 ael = *reinterpret_cast<const f16x8*>(&exl[off]);
        acc = __builtin_amdgcn_mfma_f32_32x32x16_f16(aeh, beh, acc, 0, 0, 0);
        acc2 = __builtin_amdgcn_mfma_f32_32x32x16_f16(ael, beh, acc2, 0, 0, 0);
      }
#pragma unroll
      for (int r = 0; r < 16; ++r) {
        float dv = fmaf(acc2[r], LO_INV, acc[r]);
        int cr = mt * 32 + (r & 3) + 8 * (r >> 2) + 4 * hl;
        if (dv < bestd || (dv == bestd && cr < bestc)) { bestd = dv; bestc = cr; }
      }
    }

    float od = __shfl_xor(bestd, 32, 64);
    int oc = __shfl_xor(bestc, 32, 64);
    if (od < bestd || (od == bestd && oc < bestc)) { bestd = od; bestc = oc; }

    if (hl == 0) {
      unsigned int u = __float_as_uint(bestd);
      u ^= (u & 0x80000000u) ? 0xFFFFFFFFu : 0x80000000u;  // sortable float
      unsigned long long kk =
          ((unsigned long long)u << 32) | (unsigned int)(half * 128 + bestc);
      atomicMin(&best[pt], kk);
    }
  }
}

// ---------------- combine halves: best -> idx (float+int) + counts ----------------
__global__ __launch_bounds__(1024) void k_combine(
    const unsigned long long* __restrict__ best, float* __restrict__ o_idx,
    int* __restrict__ w_idx, unsigned int* __restrict__ counts) {
  __shared__ unsigned int hist[K];
  int t = threadIdx.x;
  int p = blockIdx.x * 1024 + t;
  if (t < K) hist[t] = 0u;
  __syncthreads();
  int c = (int)(best[p] & 0xFFFFFFFFull);
  o_idx[p] = (float)c;
  w_idx[p] = c;
  atomicAdd(&hist[c], 1u);
  __syncthreads();
  if (t < K) {
    unsigned int h = hist[t];
    if (h) atomicAdd(&counts[t], h);
  }
}

// ---------------- mono assignment (fallback) ----------------
__global__ __launch_bounds__(512, 2) void k_assign_mono(
    const float* __restrict__ keys, const _Float16* __restrict__ csplit,
    const _Float16* __restrict__ extH, const _Float16* __restrict__ extL,
    float* __restrict__ out_idx, int* __restrict__ out_iidx,
    unsigned int* __restrict__ counts) {
  __shared__ __align__(16) _Float16 cs[2 * 32768];
  __shared__ __align__(16) _Float16 exh[2056], exl[2056];
  __shared__ unsigned int hist[K];

  const int tid = threadIdx.x;
  const int lane = tid & 63;
  const int wv = tid >> 6;
  const int col = lane & 31;
  const int hl = lane >> 5;

  {
    const float4* s4 = reinterpret_cast<const float4*>(csplit);
    float4* d4 = reinterpret_cast<float4*>(cs);
#pragma unroll
    for (int it = 0; it < 16; ++it) d4[tid + 512 * it] = s4[tid + 512 * it];
    if (tid < 256) {
      reinterpret_cast<float4*>(exh)[tid] = reinterpret_cast<const float4*>(extH)[tid];
      hist[tid] = 0u;
    } else if (tid < 512) {
      reinterpret_cast<float4*>(exl)[tid - 256] =
          reinterpret_cast<const float4*>(extL)[tid - 256];
    }
    if (tid < 8) { exh[2048 + tid] = (_Float16)0.0f; exl[2048 + tid] = (_Float16)0.0f; }
  }

  const size_t pt = (size_t)blockIdx.x * 256 + wv * 32 + col;
  const float* kp = keys + pt * D + hl * 8;
  f16x8 bh[8], bl[8];
#pragma unroll
  for (int kt = 0; kt < 8; ++kt) {
    float4 x0 = *reinterpret_cast<const float4*>(kp + kt * 16);
    float4 x1 = *reinterpret_cast<const float4*>(kp + kt * 16 + 4);
    float xs[8] = {x0.x, x0.y, x0.z, x0.w, x1.x, x1.y, x1.z, x1.w};
#pragma unroll
    for (int j = 0; j < 8; ++j) {
      float x = xs[j];
      _Float16 h = (_Float16)x;
      bh[kt][j] = h;
      bl[kt][j] = (_Float16)((x - (float)h) * LO_SCALE);
    }
  }
  f16x8 beh = {};
  if (hl == 0) { beh[0] = (_Float16)1.0f; beh[1] = (_Float16)1.0f; }
  __syncthreads();

  float bestd = 3.0e38f;
  int bestc = 0;
#pragma unroll
  for (int ph = 0; ph < 2; ++ph) {
    f32x16 acc[4], acc2[4];
#pragma unroll
    for (int mt = 0; mt < 4; ++mt)
#pragma unroll
      for (int r = 0; r < 16; ++r) { acc[mt][r] = 0.0f; acc2[mt][r] = 0.0f; }
#pragma unroll
    for (int kt = 0; kt < 8; ++kt) {
#pragma unroll
      for (int mt = 0; mt < 4; ++mt) {
        int c = ph * 128 + mt * 32 + col;
        int sw = (c * 128 + kt * 16 + hl * 8) ^ ((c & 15) << 3);
        f16x8 ah = *reinterpret_cast<const f16x8*>(&cs[sw]);
        f16x8 al = *reinterpret_cast<const f16x8*>(&cs[32768 + sw]);
        acc[mt] = __builtin_amdgcn_mfma_f32_32x32x16_f16(ah, bh[kt], acc[mt], 0, 0, 0);
        acc2[mt] = __builtin_amdgcn_mfma_f32_32x32x16_f16(ah, bl[kt], acc2[mt], 0, 0, 0);
        acc2[mt] = __builtin_amdgcn_mfma_f32_32x32x16_f16(al, bh[kt], acc2[mt], 0, 0, 0);
      }
    }
#pragma unroll
    for (int mt = 0; mt < 4; ++mt) {
      int c = ph * 128 + mt * 32 + col;
      int off = hl ? 2048 : c * 8;
      f16x8 aeh = *reinterpret_cast<const f16x8*>(&exh[off]);
      f16x8 ael = *reinterpret_cast<const f16x8*>(&exl[off]);
      acc[mt] = __builtin_amdgcn_mfma_f32_32x32x16_f16(aeh, beh, acc[mt], 0, 0, 0);
      acc2[mt] = __builtin_amdgcn_mfma_f32_32x32x16_f16(ael, beh, acc2[mt], 0, 0, 0);
    }
#pragma unroll
    for (int mt = 0; mt < 4; ++mt) {
#pragma unroll
      for (int r = 0; r < 16; ++r) {
        float dv = fmaf(acc2[mt][r], LO_INV, acc[mt][r]);
        int cc = ph * 128 + mt * 32 + (r & 3) + 8 * (r >> 2) + 4 * hl;
        if (dv < bestd || (dv == bestd && cc < bestc)) { bestd = dv; bestc = cc; }
      }
    }
  }
  float od = __shfl_xor(bestd, 32, 64);
  int oc = __shfl_xor(bestc, 32, 64);
  if (od < bestd || (od == bestd && oc < bestc)) { bestd = od; bestc = oc; }
  if (hl == 0) {
    out_idx[pt] = (float)bestc;
    out_iidx[pt] = bestc;
    atomicAdd(&hist[bestc], 1u);
  }
  __syncthreads();
  if (tid < K) {
    unsigned int h = hist[tid];
    if (h) atomicAdd(&counts[tid], h);
  }
}

// ---------------- exclusive prefix of counts -> cursors ----------------
__global__ __launch_bounds__(256) void k_prefix(const unsigned int* __restrict__ counts,
                                                int* __restrict__ cursor) {
  __shared__ int tmp[257];
  int t = threadIdx.x;
  tmp[t + 1] = (int)counts[t];
  if (t == 0) tmp[0] = 0;
  __syncthreads();
  int x = tmp[t + 1];
  for (int off = 1; off < 256; off <<= 1) {
    int y = (t >= off) ? tmp[t + 1 - off] : 0;
    __syncthreads();
    x += y;
    tmp[t + 1] = x;
    __syncthreads();
  }
  cursor[t] = tmp[t];
}

// ---------------- counting-sort scatter ----------------
__global__ __launch_bounds__(1024) void k_scatter(const int* __restrict__ idx,
                                                  int* __restrict__ cursor,
                                                  int* __restrict__ sorted) {
  __shared__ int lh[K];
  __shared__ int lb[K];
  int t = threadIdx.x;
  int p = blockIdx.x * 1024 + t;
  int c = idx[p];
  if (t < K) lh[t] = 0;
  __syncthreads();
  atomicAdd(&lh[c], 1);
  __syncthreads();
  if (t < K) {
    int n = lh[t];
    lb[t] = n ? atomicAdd(&cursor[t], n) : 0;
    lh[t] = 0;
  }
  __syncthreads();
  int r = atomicAdd(&lh[c], 1);
  sorted[lb[c] + r] = (c << 22) | p;
}

// ---------------- fused K+V segment sum over the sorted list ----------------
// SP=32: 8192 groups (16 waves/CU); block-merged end-of-chunk flush.
constexpr int SP = 32;
__global__ __launch_bounds__(256) void k_psum2(const float* __restrict__ keys,
                                               const float* __restrict__ values,
                                               const int* __restrict__ sorted,
                                               float* __restrict__ ksum,
                                               float* __restrict__ vsum) {
  __shared__ float part[8][256];
  __shared__ int cid[8];

  const int sub = threadIdx.x & 31;
  const int lg = threadIdx.x >> 5;
  const int grp = blockIdx.x * 8 + lg;
  const int gbase = grp * SP;
  const int off = sub * 4;

  float4 ak = make_float4(0.f, 0.f, 0.f, 0.f);
  float4 av = make_float4(0.f, 0.f, 0.f, 0.f);
  int cur = sorted[gbase] >> 22;

#define FLUSH()                                            \
  {                                                        \
    float* fa = &ksum[(cur << 7) + off];                   \
    unsafeAtomicAdd(fa + 0, ak.x);                         \
    unsafeAtomicAdd(fa + 1, ak.y);                         \
    unsafeAtomicAdd(fa + 2, ak.z);                         \
    unsafeAtomicAdd(fa + 3, ak.w);                         \
    float* fb = &vsum[(cur << 7) + off];                   \
    unsafeAtomicAdd(fb + 0, av.x);                         \
    unsafeAtomicAdd(fb + 1, av.y);                         \
    unsafeAtomicAdd(fb + 2, av.z);                         \
    unsafeAtomicAdd(fb + 3, av.w);                         \
    ak = make_float4(0.f, 0.f, 0.f, 0.f);                  \
    av = make_float4(0.f, 0.f, 0.f, 0.f);                  \
  }

  for (int i = 0; i < SP; i += 4) {
    int4 e = *reinterpret_cast<const int4*>(&sorted[gbase + i]);
    size_t p0 = (size_t)(e.x & 0x3FFFFF) * D;
    size_t p1 = (size_t)(e.y & 0x3FFFFF) * D;
    size_t p2 = (size_t)(e.z & 0x3FFFFF) * D;
    size_t p3 = (size_t)(e.w & 0x3FFFFF) * D;
    float4 k0 = *reinterpret_cast<const float4*>(keys + p0 + off);
    float4 v0 = *reinterpret_cast<const float4*>(values + p0 + off);
    float4 k1 = *reinterpret_cast<const float4*>(keys + p1 + off);
    float4 v1 = *reinterpret_cast<const float4*>(values + p1 + off);
    float4 k2 = *reinterpret_cast<const float4*>(keys + p2 + off);
    float4 v2 = *reinterpret_cast<const float4*>(values + p2 + off);
    float4 k3 = *reinterpret_cast<const float4*>(keys + p3 + off);
    float4 v3 = *reinterpret_cast<const float4*>(values + p3 + off);
    int c0 = e.x >> 22, c1 = e.y >> 22, c2 = e.z >> 22, c3 = e.w >> 22;

    if (c0 != cur) { FLUSH(); cur = c0; }
    ak.x += k0.x; ak.y += k0.y; ak.z += k0.z; ak.w += k0.w;
    av.x += v0.x; av.y += v0.y; av.z += v0.z; av.w += v0.w;
    if (c1 != cur) { FLUSH(); cur = c1; }
    ak.x += k1.x; ak.y += k1.y; ak.z += k1.z; ak.w += k1.w;
    av.x += v1.x; av.y += v1.y; av.z += v1.z; av.w += v1.w;
    if (c2 != cur) { FLUSH(); cur = c2; }
    ak.x += k2.x; ak.y += k2.y; ak.z += k2.z; ak.w += k2.w;
    av.x += v2.x; av.y += v2.y; av.z += v2.z; av.w += v2.w;
    if (c3 != cur) { FLUSH(); cur = c3; }
    ak.x += k3.x; ak.y += k3.y; ak.z += k3.z; ak.w += k3.w;
    av.x += v3.x; av.y += v3.y; av.z += v3.z; av.w += v3.w;
  }
#undef FLUSH

  *reinterpret_cast<float4*>(&part[lg][off]) = ak;
  *reinterpret_cast<float4*>(&part[lg][128 + off]) = av;
  if (sub == 0) cid[lg] = cur;
  __syncthreads();

  int c = cid[lg];
  bool owner = (lg == 0) || (cid[lg - 1] != c);
  if (owner) {
    float4 sk = make_float4(0.f, 0.f, 0.f, 0.f);
    float4 sv = make_float4(0.f, 0.f, 0.f, 0.f);
    for (int s = lg; s < 8 && cid[s] == c; ++s) {
      float4 pk = *reinterpret_cast<const float4*>(&part[s][off]);
      float4 pv = *reinterpret_cast<const float4*>(&part[s][128 + off]);
      sk.x += pk.x; sk.y += pk.y; sk.z += pk.z; sk.w += pk.w;
      sv.x += pv.x; sv.y += pv.y; sv.z += pv.z; sv.w += pv.w;
    }
    float* fa = &ksum[(c << 7) + off];
    unsafeAtomicAdd(fa + 0, sk.x);
    unsafeAtomicAdd(fa + 1, sk.y);
    unsafeAtomicAdd(fa + 2, sk.z);
    unsafeAtomicAdd(fa + 3, sk.w);
    float* fb = &vsum[(c << 7) + off];
    unsafeAtomicAdd(fb + 0, sv.x);
    unsafeAtomicAdd(fb + 1, sv.y);
    unsafeAtomicAdd(fb + 2, sv.z);
    unsafeAtomicAdd(fb + 3, sv.w);
  }
}

// ---------------- fallback psum (float idx) ----------------
__global__ __launch_bounds__(1024) void k_psum_fb(const float* __restrict__ src,
                                                  const float* __restrict__ idxf,
                                                  float* __restrict__ gacc, int ppb) {
  __shared__ float acc[K * D];
  for (int i = threadIdx.x; i < K * D; i += 1024) acc[i] = 0.f;
  __syncthreads();
  const int d = threadIdx.x & 127;
  const int ps = threadIdx.x >> 7;
  const int base = blockIdx.x * ppb;
#pragma unroll 4
  for (int p = ps; p < ppb; p += 8) {
    int c = (int)idxf[base + p];
    float v = src[(size_t)(base + p) * D + d];
    unsafeAtomicAdd(&acc[(c << 7) + d], v);
  }
  __syncthreads();
  for (int i = threadIdx.x; i < K * D; i += 1024) {
    float v = acc[i];
    if (v != 0.f) unsafeAtomicAdd(&gacc[i], v);
  }
}

// ---------------- EMA update + counts ----------------
__global__ __launch_bounds__(256) void k_finish(
    const float* __restrict__ ksum, const float* __restrict__ vsum,
    const float* __restrict__ kc, const float* __restrict__ vc,
    const float* __restrict__ oldcnt, const unsigned int* __restrict__ counts,
    float* __restrict__ ok, float* __restrict__ ov, float* __restrict__ ocnt) {
  int i = blockIdx.x * 256 + threadIdx.x;
  int c = i >> 7;
  float cnt = (float)counts[c];
  float safe = fmaxf(cnt, 1.0f);
  float km = ksum[i] / safe, vm = vsum[i] / safe;
  float okc = kc[i], ovc = vc[i];
  bool ne = cnt > 0.f;
  ok[i] = ne ? (1.0f - LR) * okc + LR * km : okc;
  ov[i] = ne ? (1.0f - LR) * ovc + LR * vm : ovc;
  if ((i & 127) == 0) ocnt[c] = oldcnt[c] + cnt;
}

extern "C" void kernel_launch(void* const* d_in, const int* in_sizes, int n_in,
                              void* d_out, int out_size, void* d_ws, size_t ws_size,
                              hipStream_t stream) {
  const float* keys = (const float*)d_in[0];
  const float* values = (const float*)d_in[1];
  const float* kcent = (const float*)d_in[2];
  const float* vcent = (const float*)d_in[3];
  const float* oldcnt = (const float*)d_in[4];
  const int N = in_sizes[0] / D;  // 262144

  float* ws = (float*)d_ws;
  unsigned int* w_counts = (unsigned int*)ws;          // 0      .. 256
  float* w_ksum = ws + 256;                            // 256    .. 33024
  float* w_vsum = ws + 33024;                          // 33024  .. 65792
  _Float16* w_csplit = (_Float16*)(ws + 65792);        // 65792  .. 98560
  _Float16* w_extH = w_csplit + 65536;                 // 98560  .. 99584
  _Float16* w_extL = w_extH + 2048;                    // 99584  .. 100608
  int* w_idx = (int*)(ws + 100608);                    // 100608 .. 362752
  int* w_cursor = (int*)(ws + 100608 + N);             // 362752 .. 363008
  float* w_X = ws + 363008;                            // best (2N f) / sorted (N f)
  unsigned long long* w_best = (unsigned long long*)w_X;
  int* w_sorted = (int*)w_X;

  float* o_idx = (float*)d_out;  // N
  float* o_kc = o_idx + N;       // K*D
  float* o_vc = o_kc + K * D;    // K*D
  float* o_cnt = o_vc + K * D;   // K

  size_t need_split = (size_t)(363008 + 2 * N) * 4;
  size_t need_mono = (size_t)(363008 + N) * 4;
  bool split_path = ws_size >= need_split;
  bool mono_sorted = !split_path && ws_size >= need_mono;

  int zn = 256 + 2 * K * D;  // counts + ksum + vsum
  k_zero<<<(zn + 255) / 256, 256, 0, stream>>>(ws, zn);
  k_prep<<<K, 128, 0, stream>>>(kcent, w_csplit, w_extH, w_extL, split_path ? 1 : 0);

  if (split_path) {
    k_init_best<<<N / 256, 256, 0, stream>>>(w_best);
    const int T = 2;  // 512-point iterations per block -> grid 512 = 2 blocks/CU
    k_assign2<<<(N / (512 * T)) * 2, 1024, 0, stream>>>(keys, w_csplit, w_extH,
                                                        w_extL, w_best, T);
    k_combine<<<N / 1024, 1024, 0, stream>>>(w_best, o_idx, w_idx, w_counts);
    k_prefix<<<1, 256, 0, stream>>>(w_counts, w_cursor);
    k_scatter<<<N / 1024, 1024, 0, stream>>>(w_idx, w_cursor, w_sorted);
    k_psum2<<<N / (SP * 8), 256, 0, stream>>>(keys, values, w_sorted, w_ksum, w_vsum);
  } else {
    k_assign_mono<<<N / 256, 512, 0, stream>>>(keys, w_csplit, w_extH, w_extL, o_idx,
                                               mono_sorted ? w_idx : w_cursor,
                                               w_counts);
    if (mono_sorted) {
      k_prefix<<<1, 256, 0, stream>>>(w_counts, w_cursor);
      k_scatter<<<N / 1024, 1024, 0, stream>>>(w_idx, w_cursor, w_sorted);
      k_psum2<<<N / (SP * 8), 256, 0, stream>>>(keys, values, w_sorted, w_ksum, w_vsum);
    } else {
      int ppb = N / 256;
      k_psum_fb<<<256, 1024, 0, stream>>>(keys, o_idx, w_ksum, ppb);
      k_psum_fb<<<256, 1024, 0, stream>>>(values, o_idx, w_vsum, ppb);
    }
  }
  k_finish<<<(K * D) / 256, 256, 0, stream>>>(w_ksum, w_vsum, kcent, vcent, oldcnt,
                                              w_counts, o_kc, o_vc, o_cnt);
}

// Round 11
// 165.634 us; speedup vs baseline: 1.7580x; 1.7580x over previous
//
#include <hip/hip_runtime.h>

typedef _Float16 f16x8 __attribute__((ext_vector_type(8)));
typedef float f32x16 __attribute__((ext_vector_type(16)));

constexpr int D = 128;
constexpr int K = 256;
constexpr float LR = 0.01f;
constexpr float LO_SCALE = 4096.0f;
constexpr float LO_INV = 1.0f / 4096.0f;

// ---------------- zero ws ----------------
__global__ __launch_bounds__(256) void k_zero(float* p, int n) {
  int i = blockIdx.x * 256 + threadIdx.x;
  if (i < n) p[i] = 0.0f;
}

__global__ __launch_bounds__(256) void k_init_best(unsigned long long* b) {
  b[blockIdx.x * 256 + threadIdx.x] = ~0ull;
}

// ---------------- prep: split centroids (prescaled by -2) + cnorm extension ---------
// mode 2: quarter layout  csplit[(c>>6)*16384 + part*8192 + sw(c&63,k)]
// mode 0: mono layout     csplit[part*32768 + sw(c,k)]
__global__ __launch_bounds__(128) void k_prep(const float* __restrict__ cent,
                                              _Float16* __restrict__ csplit,
                                              _Float16* __restrict__ extH,
                                              _Float16* __restrict__ extL, int mode) {
  int c = blockIdx.x, k = threadIdx.x;
  float x = cent[c * D + k];
  float ca = -2.0f * x;
  _Float16 h = (_Float16)ca;
  float r = ca - (float)h;
  _Float16 lo = (_Float16)(r * LO_SCALE);
  if (mode == 2) {
    int cc = c & 63;
    int base = (c >> 6) * 16384;
    int sw = (cc * 128 + k) ^ ((cc & 15) << 3);
    csplit[base + sw] = h;
    csplit[base + 8192 + sw] = lo;
  } else {
    int sw = (c * 128 + k) ^ ((c & 15) << 3);
    csplit[sw] = h;
    csplit[32768 + sw] = lo;
  }

  float s = x * x;
#pragma unroll
  for (int off = 32; off; off >>= 1) s += __shfl_down(s, off, 64);
  __shared__ float w0;
  if (k == 0) w0 = s;
  __syncthreads();
  if (k == 64) {
    float cn = w0 + s;
    _Float16 c1 = (_Float16)cn;
    float rr = cn - (float)c1;
    _Float16 c2s = (_Float16)(rr * LO_SCALE);
    float rr2 = rr - (float)c2s * LO_INV;
    _Float16 c3s = (_Float16)(rr2 * LO_SCALE);
    extH[c * 8 + 0] = c1;
    extL[c * 8 + 0] = c2s;
    extL[c * 8 + 1] = c3s;
  }
  if (k >= 1 && k < 8) extH[c * 8 + k] = (_Float16)0.0f;
  if (k >= 2 && k < 8) extL[c * 8 + k] = (_Float16)0.0f;
}

// ---------------- assignment v4: 4-way cluster split, 34.3 KB LDS, 4 blocks/CU ----
// bid&3 = cluster quarter (64 clusters in LDS); 512 thr (8 waves), VGPR~64 ->
// 8 waves/EU -> 32 waves/CU. Merge via u64 atomicMin (exact tie-break).
__global__ __launch_bounds__(512, 4) void k_assign2(
    const float* __restrict__ keys, const _Float16* __restrict__ csplit,
    const _Float16* __restrict__ extH, const _Float16* __restrict__ extL,
    unsigned long long* __restrict__ best, int T) {
  __shared__ __align__(16) _Float16 csH[8192];  // 16 KB (64 clusters)
  __shared__ __align__(16) _Float16 csL[8192];  // 16 KB
  __shared__ __align__(16) _Float16 exh[520], exl[520];

  const int tid = threadIdx.x;
  const int lane = tid & 63;
  const int wv = tid >> 6;
  const int col = lane & 31;
  const int hl = lane >> 5;
  const int q = blockIdx.x & 3;
  const size_t base_pt = (size_t)(blockIdx.x >> 2) * 256 * T;

  // stage 34 KB (L2/L3-hot)
  {
    const float4* sH = reinterpret_cast<const float4*>(csplit + q * 16384);
    const float4* sL = reinterpret_cast<const float4*>(csplit + q * 16384 + 8192);
    float4* dH = reinterpret_cast<float4*>(csH);
    float4* dL = reinterpret_cast<float4*>(csL);
#pragma unroll
    for (int it = 0; it < 2; ++it) {
      dH[tid + 512 * it] = sH[tid + 512 * it];
      dL[tid + 512 * it] = sL[tid + 512 * it];
    }
    if (tid < 64)
      reinterpret_cast<float4*>(exh)[tid] =
          reinterpret_cast<const float4*>(extH + q * 512)[tid];
    else if (tid < 128)
      reinterpret_cast<float4*>(exl)[tid - 64] =
          reinterpret_cast<const float4*>(extL + q * 512)[tid - 64];
    if (tid < 8) { exh[512 + tid] = (_Float16)0.0f; exl[512 + tid] = (_Float16)0.0f; }
  }

  f16x8 beh = {};
  if (hl == 0) { beh[0] = (_Float16)1.0f; beh[1] = (_Float16)1.0f; }
  __syncthreads();

#pragma unroll 1
  for (int t = 0; t < T; ++t) {
    const size_t pt = base_pt + (size_t)t * 256 + wv * 32 + col;
    f16x8 bh[8], bl[8];
    {
      const float* kp = keys + pt * D + hl * 8;
#pragma unroll
      for (int kt = 0; kt < 8; ++kt) {
        float4 x0 = *reinterpret_cast<const float4*>(kp + kt * 16);
        float4 x1 = *reinterpret_cast<const float4*>(kp + kt * 16 + 4);
        float xs[8] = {x0.x, x0.y, x0.z, x0.w, x1.x, x1.y, x1.z, x1.w};
#pragma unroll
        for (int j = 0; j < 8; ++j) {
          float x = xs[j];
          _Float16 h = (_Float16)x;
          bh[kt][j] = h;
          bl[kt][j] = (_Float16)((x - (float)h) * LO_SCALE);
        }
      }
    }

    float bestd = 3.0e38f;
    int bestc = 0;
#pragma unroll 1
    for (int mt = 0; mt < 2; ++mt) {
      f32x16 acc, acc2;
#pragma unroll
      for (int r = 0; r < 16; ++r) { acc[r] = 0.0f; acc2[r] = 0.0f; }
      const int cc = mt * 32 + col;
#pragma unroll
      for (int kt = 0; kt < 8; ++kt) {
        int sw = (cc * 128 + kt * 16 + hl * 8) ^ ((cc & 15) << 3);
        f16x8 ah = *reinterpret_cast<const f16x8*>(&csH[sw]);
        f16x8 al = *reinterpret_cast<const f16x8*>(&csL[sw]);
        acc = __builtin_amdgcn_mfma_f32_32x32x16_f16(ah, bh[kt], acc, 0, 0, 0);
        acc2 = __builtin_amdgcn_mfma_f32_32x32x16_f16(ah, bl[kt], acc2, 0, 0, 0);
        acc2 = __builtin_amdgcn_mfma_f32_32x32x16_f16(al, bh[kt], acc2, 0, 0, 0);
      }
      {
        int off = hl ? 512 : cc * 8;
        f16x8 aeh = *reinterpret_cast<const f16x8*>(&exh[off]);
        f16x8 ael = *reinterpret_cast<const f16x8*>(&exl[off]);
        acc = __builtin_amdgcn_mfma_f32_32x32x16_f16(aeh, beh, acc, 0, 0, 0);
        acc2 = __builtin_amdgcn_mfma_f32_32x32x16_f16(ael, beh, acc2, 0, 0, 0);
      }
#pragma unroll
      for (int r = 0; r < 16; ++r) {
        float dv = fmaf(acc2[r], LO_INV, acc[r]);
        int cr = mt * 32 + (r & 3) + 8 * (r >> 2) + 4 * hl;
        if (dv < bestd || (dv == bestd && cr < bestc)) { bestd = dv; bestc = cr; }
      }
    }

    float od = __shfl_xor(bestd, 32, 64);
    int oc = __shfl_xor(bestc, 32, 64);
    if (od < bestd || (od == bestd && oc < bestc)) { bestd = od; bestc = oc; }

    if (hl == 0) {
      unsigned int u = __float_as_uint(bestd);
      u ^= (u & 0x80000000u) ? 0xFFFFFFFFu : 0x80000000u;  // sortable float
      unsigned long long kk =
          ((unsigned long long)u << 32) | (unsigned int)(q * 64 + bestc);
      atomicMin(&best[pt], kk);
    }
  }
}

// ---------------- combine: best -> idx (float+int) + counts ----------------
__global__ __launch_bounds__(1024) void k_combine(
    const unsigned long long* __restrict__ best, float* __restrict__ o_idx,
    int* __restrict__ w_idx, unsigned int* __restrict__ counts) {
  __shared__ unsigned int hist[K];
  int t = threadIdx.x;
  int p = blockIdx.x * 1024 + t;
  if (t < K) hist[t] = 0u;
  __syncthreads();
  int c = (int)(best[p] & 0xFFFFFFFFull);
  o_idx[p] = (float)c;
  w_idx[p] = c;
  atomicAdd(&hist[c], 1u);
  __syncthreads();
  if (t < K) {
    unsigned int h = hist[t];
    if (h) atomicAdd(&counts[t], h);
  }
}

// ---------------- mono assignment (fallback) ----------------
__global__ __launch_bounds__(512, 2) void k_assign_mono(
    const float* __restrict__ keys, const _Float16* __restrict__ csplit,
    const _Float16* __restrict__ extH, const _Float16* __restrict__ extL,
    float* __restrict__ out_idx, int* __restrict__ out_iidx,
    unsigned int* __restrict__ counts) {
  __shared__ __align__(16) _Float16 cs[2 * 32768];
  __shared__ __align__(16) _Float16 exh[2056], exl[2056];
  __shared__ unsigned int hist[K];

  const int tid = threadIdx.x;
  const int lane = tid & 63;
  const int wv = tid >> 6;
  const int col = lane & 31;
  const int hl = lane >> 5;

  {
    const float4* s4 = reinterpret_cast<const float4*>(csplit);
    float4* d4 = reinterpret_cast<float4*>(cs);
#pragma unroll
    for (int it = 0; it < 16; ++it) d4[tid + 512 * it] = s4[tid + 512 * it];
    if (tid < 256) {
      reinterpret_cast<float4*>(exh)[tid] = reinterpret_cast<const float4*>(extH)[tid];
      hist[tid] = 0u;
    } else if (tid < 512) {
      reinterpret_cast<float4*>(exl)[tid - 256] =
          reinterpret_cast<const float4*>(extL)[tid - 256];
    }
    if (tid < 8) { exh[2048 + tid] = (_Float16)0.0f; exl[2048 + tid] = (_Float16)0.0f; }
  }

  const size_t pt = (size_t)blockIdx.x * 256 + wv * 32 + col;
  const float* kp = keys + pt * D + hl * 8;
  f16x8 bh[8], bl[8];
#pragma unroll
  for (int kt = 0; kt < 8; ++kt) {
    float4 x0 = *reinterpret_cast<const float4*>(kp + kt * 16);
    float4 x1 = *reinterpret_cast<const float4*>(kp + kt * 16 + 4);
    float xs[8] = {x0.x, x0.y, x0.z, x0.w, x1.x, x1.y, x1.z, x1.w};
#pragma unroll
    for (int j = 0; j < 8; ++j) {
      float x = xs[j];
      _Float16 h = (_Float16)x;
      bh[kt][j] = h;
      bl[kt][j] = (_Float16)((x - (float)h) * LO_SCALE);
    }
  }
  f16x8 beh = {};
  if (hl == 0) { beh[0] = (_Float16)1.0f; beh[1] = (_Float16)1.0f; }
  __syncthreads();

  float bestd = 3.0e38f;
  int bestc = 0;
#pragma unroll
  for (int ph = 0; ph < 2; ++ph) {
    f32x16 acc[4], acc2[4];
#pragma unroll
    for (int mt = 0; mt < 4; ++mt)
#pragma unroll
      for (int r = 0; r < 16; ++r) { acc[mt][r] = 0.0f; acc2[mt][r] = 0.0f; }
#pragma unroll
    for (int kt = 0; kt < 8; ++kt) {
#pragma unroll
      for (int mt = 0; mt < 4; ++mt) {
        int c = ph * 128 + mt * 32 + col;
        int sw = (c * 128 + kt * 16 + hl * 8) ^ ((c & 15) << 3);
        f16x8 ah = *reinterpret_cast<const f16x8*>(&cs[sw]);
        f16x8 al = *reinterpret_cast<const f16x8*>(&cs[32768 + sw]);
        acc[mt] = __builtin_amdgcn_mfma_f32_32x32x16_f16(ah, bh[kt], acc[mt], 0, 0, 0);
        acc2[mt] = __builtin_amdgcn_mfma_f32_32x32x16_f16(ah, bl[kt], acc2[mt], 0, 0, 0);
        acc2[mt] = __builtin_amdgcn_mfma_f32_32x32x16_f16(al, bh[kt], acc2[mt], 0, 0, 0);
      }
    }
#pragma unroll
    for (int mt = 0; mt < 4; ++mt) {
      int c = ph * 128 + mt * 32 + col;
      int off = hl ? 2048 : c * 8;
      f16x8 aeh = *reinterpret_cast<const f16x8*>(&exh[off]);
      f16x8 ael = *reinterpret_cast<const f16x8*>(&exl[off]);
      acc[mt] = __builtin_amdgcn_mfma_f32_32x32x16_f16(aeh, beh, acc[mt], 0, 0, 0);
      acc2[mt] = __builtin_amdgcn_mfma_f32_32x32x16_f16(ael, beh, acc2[mt], 0, 0, 0);
    }
#pragma unroll
    for (int mt = 0; mt < 4; ++mt) {
#pragma unroll
      for (int r = 0; r < 16; ++r) {
        float dv = fmaf(acc2[mt][r], LO_INV, acc[mt][r]);
        int cc = ph * 128 + mt * 32 + (r & 3) + 8 * (r >> 2) + 4 * hl;
        if (dv < bestd || (dv == bestd && cc < bestc)) { bestd = dv; bestc = cc; }
      }
    }
  }
  float od = __shfl_xor(bestd, 32, 64);
  int oc = __shfl_xor(bestc, 32, 64);
  if (od < bestd || (od == bestd && oc < bestc)) { bestd = od; bestc = oc; }
  if (hl == 0) {
    out_idx[pt] = (float)bestc;
    out_iidx[pt] = bestc;
    atomicAdd(&hist[bestc], 1u);
  }
  __syncthreads();
  if (tid < K) {
    unsigned int h = hist[tid];
    if (h) atomicAdd(&counts[tid], h);
  }
}

// ---------------- exclusive prefix of counts -> cursors ----------------
__global__ __launch_bounds__(256) void k_prefix(const unsigned int* __restrict__ counts,
                                                int* __restrict__ cursor) {
  __shared__ int tmp[257];
  int t = threadIdx.x;
  tmp[t + 1] = (int)counts[t];
  if (t == 0) tmp[0] = 0;
  __syncthreads();
  int x = tmp[t + 1];
  for (int off = 1; off < 256; off <<= 1) {
    int y = (t >= off) ? tmp[t + 1 - off] : 0;
    __syncthreads();
    x += y;
    tmp[t + 1] = x;
    __syncthreads();
  }
  cursor[t] = tmp[t];
}

// ---------------- counting-sort scatter ----------------
__global__ __launch_bounds__(1024) void k_scatter(const int* __restrict__ idx,
                                                  int* __restrict__ cursor,
                                                  int* __restrict__ sorted) {
  __shared__ int lh[K];
  __shared__ int lb[K];
  int t = threadIdx.x;
  int p = blockIdx.x * 1024 + t;
  int c = idx[p];
  if (t < K) lh[t] = 0;
  __syncthreads();
  atomicAdd(&lh[c], 1);
  __syncthreads();
  if (t < K) {
    int n = lh[t];
    lb[t] = n ? atomicAdd(&cursor[t], n) : 0;
    lh[t] = 0;
  }
  __syncthreads();
  int r = atomicAdd(&lh[c], 1);
  sorted[lb[c] + r] = (c << 22) | p;
}

// ---------------- fused K+V segment sum over the sorted list ----------------
constexpr int SP = 32;
__global__ __launch_bounds__(256) void k_psum2(const float* __restrict__ keys,
                                               const float* __restrict__ values,
                                               const int* __restrict__ sorted,
                                               float* __restrict__ ksum,
                                               float* __restrict__ vsum) {
  __shared__ float part[8][256];
  __shared__ int cid[8];

  const int sub = threadIdx.x & 31;
  const int lg = threadIdx.x >> 5;
  const int grp = blockIdx.x * 8 + lg;
  const int gbase = grp * SP;
  const int off = sub * 4;

  float4 ak = make_float4(0.f, 0.f, 0.f, 0.f);
  float4 av = make_float4(0.f, 0.f, 0.f, 0.f);
  int cur = sorted[gbase] >> 22;

#define FLUSH()                                            \
  {                                                        \
    float* fa = &ksum[(cur << 7) + off];                   \
    unsafeAtomicAdd(fa + 0, ak.x);                         \
    unsafeAtomicAdd(fa + 1, ak.y);                         \
    unsafeAtomicAdd(fa + 2, ak.z);                         \
    unsafeAtomicAdd(fa + 3, ak.w);                         \
    float* fb = &vsum[(cur << 7) + off];                   \
    unsafeAtomicAdd(fb + 0, av.x);                         \
    unsafeAtomicAdd(fb + 1, av.y);                         \
    unsafeAtomicAdd(fb + 2, av.z);                         \
    unsafeAtomicAdd(fb + 3, av.w);                         \
    ak = make_float4(0.f, 0.f, 0.f, 0.f);                  \
    av = make_float4(0.f, 0.f, 0.f, 0.f);                  \
  }

  for (int i = 0; i < SP; i += 4) {
    int4 e = *reinterpret_cast<const int4*>(&sorted[gbase + i]);
    size_t p0 = (size_t)(e.x & 0x3FFFFF) * D;
    size_t p1 = (size_t)(e.y & 0x3FFFFF) * D;
    size_t p2 = (size_t)(e.z & 0x3FFFFF) * D;
    size_t p3 = (size_t)(e.w & 0x3FFFFF) * D;
    float4 k0 = *reinterpret_cast<const float4*>(keys + p0 + off);
    float4 v0 = *reinterpret_cast<const float4*>(values + p0 + off);
    float4 k1 = *reinterpret_cast<const float4*>(keys + p1 + off);
    float4 v1 = *reinterpret_cast<const float4*>(values + p1 + off);
    float4 k2 = *reinterpret_cast<const float4*>(keys + p2 + off);
    float4 v2 = *reinterpret_cast<const float4*>(values + p2 + off);
    float4 k3 = *reinterpret_cast<const float4*>(keys + p3 + off);
    float4 v3 = *reinterpret_cast<const float4*>(values + p3 + off);
    int c0 = e.x >> 22, c1 = e.y >> 22, c2 = e.z >> 22, c3 = e.w >> 22;

    if (c0 != cur) { FLUSH(); cur = c0; }
    ak.x += k0.x; ak.y += k0.y; ak.z += k0.z; ak.w += k0.w;
    av.x += v0.x; av.y += v0.y; av.z += v0.z; av.w += v0.w;
    if (c1 != cur) { FLUSH(); cur = c1; }
    ak.x += k1.x; ak.y += k1.y; ak.z += k1.z; ak.w += k1.w;
    av.x += v1.x; av.y += v1.y; av.z += v1.z; av.w += v1.w;
    if (c2 != cur) { FLUSH(); cur = c2; }
    ak.x += k2.x; ak.y += k2.y; ak.z += k2.z; ak.w += k2.w;
    av.x += v2.x; av.y += v2.y; av.z += v2.z; av.w += v2.w;
    if (c3 != cur) { FLUSH(); cur = c3; }
    ak.x += k3.x; ak.y += k3.y; ak.z += k3.z; ak.w += k3.w;
    av.x += v3.x; av.y += v3.y; av.z += v3.z; av.w += v3.w;
  }
#undef FLUSH

  *reinterpret_cast<float4*>(&part[lg][off]) = ak;
  *reinterpret_cast<float4*>(&part[lg][128 + off]) = av;
  if (sub == 0) cid[lg] = cur;
  __syncthreads();

  int c = cid[lg];
  bool owner = (lg == 0) || (cid[lg - 1] != c);
  if (owner) {
    float4 sk = make_float4(0.f, 0.f, 0.f, 0.f);
    float4 sv = make_float4(0.f, 0.f, 0.f, 0.f);
    for (int s = lg; s < 8 && cid[s] == c; ++s) {
      float4 pk = *reinterpret_cast<const float4*>(&part[s][off]);
      float4 pv = *reinterpret_cast<const float4*>(&part[s][128 + off]);
      sk.x += pk.x; sk.y += pk.y; sk.z += pk.z; sk.w += pk.w;
      sv.x += pv.x; sv.y += pv.y; sv.z += pv.z; sv.w += pv.w;
    }
    float* fa = &ksum[(c << 7) + off];
    unsafeAtomicAdd(fa + 0, sk.x);
    unsafeAtomicAdd(fa + 1, sk.y);
    unsafeAtomicAdd(fa + 2, sk.z);
    unsafeAtomicAdd(fa + 3, sk.w);
    float* fb = &vsum[(c << 7) + off];
    unsafeAtomicAdd(fb + 0, sv.x);
    unsafeAtomicAdd(fb + 1, sv.y);
    unsafeAtomicAdd(fb + 2, sv.z);
    unsafeAtomicAdd(fb + 3, sv.w);
  }
}

// ---------------- fallback psum (float idx) ----------------
__global__ __launch_bounds__(1024) void k_psum_fb(const float* __restrict__ src,
                                                  const float* __restrict__ idxf,
                                                  float* __restrict__ gacc, int ppb) {
  __shared__ float acc[K * D];
  for (int i = threadIdx.x; i < K * D; i += 1024) acc[i] = 0.f;
  __syncthreads();
  const int d = threadIdx.x & 127;
  const int ps = threadIdx.x >> 7;
  const int base = blockIdx.x * ppb;
#pragma unroll 4
  for (int p = ps; p < ppb; p += 8) {
    int c = (int)idxf[base + p];
    float v = src[(size_t)(base + p) * D + d];
    unsafeAtomicAdd(&acc[(c << 7) + d], v);
  }
  __syncthreads();
  for (int i = threadIdx.x; i < K * D; i += 1024) {
    float v = acc[i];
    if (v != 0.f) unsafeAtomicAdd(&gacc[i], v);
  }
}

// ---------------- EMA update + counts ----------------
__global__ __launch_bounds__(256) void k_finish(
    const float* __restrict__ ksum, const float* __restrict__ vsum,
    const float* __restrict__ kc, const float* __restrict__ vc,
    const float* __restrict__ oldcnt, const unsigned int* __restrict__ counts,
    float* __restrict__ ok, float* __restrict__ ov, float* __restrict__ ocnt) {
  int i = blockIdx.x * 256 + threadIdx.x;
  int c = i >> 7;
  float cnt = (float)counts[c];
  float safe = fmaxf(cnt, 1.0f);
  float km = ksum[i] / safe, vm = vsum[i] / safe;
  float okc = kc[i], ovc = vc[i];
  bool ne = cnt > 0.f;
  ok[i] = ne ? (1.0f - LR) * okc + LR * km : okc;
  ov[i] = ne ? (1.0f - LR) * ovc + LR * vm : ovc;
  if ((i & 127) == 0) ocnt[c] = oldcnt[c] + cnt;
}

extern "C" void kernel_launch(void* const* d_in, const int* in_sizes, int n_in,
                              void* d_out, int out_size, void* d_ws, size_t ws_size,
                              hipStream_t stream) {
  const float* keys = (const float*)d_in[0];
  const float* values = (const float*)d_in[1];
  const float* kcent = (const float*)d_in[2];
  const float* vcent = (const float*)d_in[3];
  const float* oldcnt = (const float*)d_in[4];
  const int N = in_sizes[0] / D;  // 262144

  float* ws = (float*)d_ws;
  unsigned int* w_counts = (unsigned int*)ws;          // 0      .. 256
  float* w_ksum = ws + 256;                            // 256    .. 33024
  float* w_vsum = ws + 33024;                          // 33024  .. 65792
  _Float16* w_csplit = (_Float16*)(ws + 65792);        // 65792  .. 98560
  _Float16* w_extH = w_csplit + 65536;                 // 98560  .. 99584
  _Float16* w_extL = w_extH + 2048;                    // 99584  .. 100608
  int* w_idx = (int*)(ws + 100608);                    // 100608 .. 362752
  int* w_cursor = (int*)(ws + 100608 + N);             // 362752 .. 363008
  float* w_X = ws + 363008;                            // best (2N f) / sorted (N f)
  unsigned long long* w_best = (unsigned long long*)w_X;
  int* w_sorted = (int*)w_X;

  float* o_idx = (float*)d_out;  // N
  float* o_kc = o_idx + N;       // K*D
  float* o_vc = o_kc + K * D;    // K*D
  float* o_cnt = o_vc + K * D;   // K

  size_t need_split = (size_t)(363008 + 2 * N) * 4;
  size_t need_mono = (size_t)(363008 + N) * 4;
  bool split_path = ws_size >= need_split;
  bool mono_sorted = !split_path && ws_size >= need_mono;

  int zn = 256 + 2 * K * D;  // counts + ksum + vsum
  k_zero<<<(zn + 255) / 256, 256, 0, stream>>>(ws, zn);
  k_prep<<<K, 128, 0, stream>>>(kcent, w_csplit, w_extH, w_extL, split_path ? 2 : 0);

  if (split_path) {
    k_init_best<<<N / 256, 256, 0, stream>>>(w_best);
    const int T = 4;  // 256-pt tiles per block -> grid 1024 = 4 blocks/CU, 1 round
    k_assign2<<<(N / (256 * T)) * 4, 512, 0, stream>>>(keys, w_csplit, w_extH,
                                                       w_extL, w_best, T);
    k_combine<<<N / 1024, 1024, 0, stream>>>(w_best, o_idx, w_idx, w_counts);
    k_prefix<<<1, 256, 0, stream>>>(w_counts, w_cursor);
    k_scatter<<<N / 1024, 1024, 0, stream>>>(w_idx, w_cursor, w_sorted);
    k_psum2<<<N / (SP * 8), 256, 0, stream>>>(keys, values, w_sorted, w_ksum, w_vsum);
  } else {
    k_assign_mono<<<N / 256, 512, 0, stream>>>(keys, w_csplit, w_extH, w_extL, o_idx,
                                               mono_sorted ? w_idx : w_cursor,
                                               w_counts);
    if (mono_sorted) {
      k_prefix<<<1, 256, 0, stream>>>(w_counts, w_cursor);
      k_scatter<<<N / 1024, 1024, 0, stream>>>(w_idx, w_cursor, w_sorted);
      k_psum2<<<N / (SP * 8), 256, 0, stream>>>(keys, values, w_sorted, w_ksum, w_vsum);
    } else {
      int ppb = N / 256;
      k_psum_fb<<<256, 1024, 0, stream>>>(keys, o_idx, w_ksum, ppb);
      k_psum_fb<<<256, 1024, 0, stream>>>(values, o_idx, w_vsum, ppb);
    }
  }
  k_finish<<<(K * D) / 256, 256, 0, stream>>>(w_ksum, w_vsum, kcent, vcent, oldcnt,
                                              w_counts, o_kc, o_vc, o_cnt);
}

// Round 12
// 126.154 us; speedup vs baseline: 2.3081x; 1.3130x over previous
//
#include <hip/hip_runtime.h>

typedef _Float16 f16x8 __attribute__((ext_vector_type(8)));
typedef float f32x16 __attribute__((ext_vector_type(16)));

constexpr int D = 128;
constexpr int K = 256;
constexpr float LR = 0.01f;
constexpr float LO_SCALE = 4096.0f;
constexpr float LO_INV = 1.0f / 4096.0f;

// ---------------- zero ws ----------------
__global__ __launch_bounds__(256) void k_zero(float* p, int n) {
  int i = blockIdx.x * 256 + threadIdx.x;
  if (i < n) p[i] = 0.0f;
}

// ---------------- prep: split centroids (prescaled by -2) + cnorm extension --------
// mono layout: csplit[part*32768 + sw(c,k)], sw = (c*128+k) ^ ((c&15)<<3)
__global__ __launch_bounds__(128) void k_prep(const float* __restrict__ cent,
                                              _Float16* __restrict__ csplit,
                                              _Float16* __restrict__ extH,
                                              _Float16* __restrict__ extL) {
  int c = blockIdx.x, k = threadIdx.x;
  float x = cent[c * D + k];
  float ca = -2.0f * x;
  _Float16 h = (_Float16)ca;
  float r = ca - (float)h;
  _Float16 lo = (_Float16)(r * LO_SCALE);
  int sw = (c * 128 + k) ^ ((c & 15) << 3);
  csplit[sw] = h;
  csplit[32768 + sw] = lo;

  float s = x * x;
#pragma unroll
  for (int off = 32; off; off >>= 1) s += __shfl_down(s, off, 64);
  __shared__ float w0;
  if (k == 0) w0 = s;
  __syncthreads();
  if (k == 64) {
    float cn = w0 + s;
    _Float16 c1 = (_Float16)cn;
    float rr = cn - (float)c1;
    _Float16 c2s = (_Float16)(rr * LO_SCALE);
    float rr2 = rr - (float)c2s * LO_INV;
    _Float16 c3s = (_Float16)(rr2 * LO_SCALE);
    extH[c * 8 + 0] = c1;
    extL[c * 8 + 0] = c2s;
    extL[c * 8 + 1] = c3s;
  }
  if (k >= 1 && k < 8) extH[c * 8 + k] = (_Float16)0.0f;
  if (k >= 2 && k < 8) extL[c * 8 + k] = (_Float16)0.0f;
}

// ---------------- assignment v5: mono centroids, 1024-thr block, 16 waves/CU ------
// All 256 clusters in 137.5 KB LDS; 1 block/CU (grid 256), T tiles of 512 points.
// Keys read+converted ONCE (no cluster-split redundancy). Register-lean inner loop
// (single acc/acc2 live, unroll 1 over 8 cluster groups) -> VGPR ~64-116 <= 128 cap.
__global__ __launch_bounds__(1024, 4) void k_assign(
    const float* __restrict__ keys, const _Float16* __restrict__ csplit,
    const _Float16* __restrict__ extH, const _Float16* __restrict__ extL,
    float* __restrict__ out_idx, int* __restrict__ out_iidx,
    unsigned int* __restrict__ counts, int T) {
  __shared__ __align__(16) _Float16 cs[2 * 32768];        // 128 KB
  __shared__ __align__(16) _Float16 exh[2056], exl[2056]; // 8.2 KB
  __shared__ unsigned int hist[K];                        // 1 KB

  const int tid = threadIdx.x;
  const int lane = tid & 63;
  const int wv = tid >> 6;   // 0..15
  const int col = lane & 31;
  const int hl = lane >> 5;
  const size_t base_pt = (size_t)blockIdx.x * 512 * T;

  // ---- stage 137 KB once (L2/L3-hot), 1024 threads ----
  {
    const float4* s4 = reinterpret_cast<const float4*>(csplit);
    float4* d4 = reinterpret_cast<float4*>(cs);
#pragma unroll
    for (int it = 0; it < 4; ++it) d4[tid + 1024 * it] = s4[tid + 1024 * it];
    if (tid < 256)
      reinterpret_cast<float4*>(exh)[tid] = reinterpret_cast<const float4*>(extH)[tid];
    else if (tid < 512)
      reinterpret_cast<float4*>(exl)[tid - 256] =
          reinterpret_cast<const float4*>(extL)[tid - 256];
    if (tid < 8) { exh[2048 + tid] = (_Float16)0.0f; exl[2048 + tid] = (_Float16)0.0f; }
    if (tid < K) hist[tid] = 0u;
  }

  f16x8 beh = {};
  if (hl == 0) { beh[0] = (_Float16)1.0f; beh[1] = (_Float16)1.0f; }
  __syncthreads();

#pragma unroll 1
  for (int t = 0; t < T; ++t) {
    const size_t pt = base_pt + (size_t)t * 512 + wv * 32 + col;
    // load + split this lane's key (raw dies into bh/bl before MFMA: no spill)
    f16x8 bh[8], bl[8];
    {
      const float* kp = keys + pt * D + hl * 8;
#pragma unroll
      for (int kt = 0; kt < 8; ++kt) {
        float4 x0 = *reinterpret_cast<const float4*>(kp + kt * 16);
        float4 x1 = *reinterpret_cast<const float4*>(kp + kt * 16 + 4);
        float xs[8] = {x0.x, x0.y, x0.z, x0.w, x1.x, x1.y, x1.z, x1.w};
#pragma unroll
        for (int j = 0; j < 8; ++j) {
          float x = xs[j];
          _Float16 h = (_Float16)x;
          bh[kt][j] = h;
          bl[kt][j] = (_Float16)((x - (float)h) * LO_SCALE);
        }
      }
    }

    float bestd = 3.0e38f;
    int bestc = 0;
#pragma unroll 1
    for (int mt = 0; mt < 8; ++mt) {
      f32x16 acc, acc2;
#pragma unroll
      for (int r = 0; r < 16; ++r) { acc[r] = 0.0f; acc2[r] = 0.0f; }
      const int cc = mt * 32 + col;
#pragma unroll
      for (int kt = 0; kt < 8; ++kt) {
        int sw = (cc * 128 + kt * 16 + hl * 8) ^ ((cc & 15) << 3);
        f16x8 ah = *reinterpret_cast<const f16x8*>(&cs[sw]);
        f16x8 al = *reinterpret_cast<const f16x8*>(&cs[32768 + sw]);
        acc = __builtin_amdgcn_mfma_f32_32x32x16_f16(ah, bh[kt], acc, 0, 0, 0);
        acc2 = __builtin_amdgcn_mfma_f32_32x32x16_f16(ah, bl[kt], acc2, 0, 0, 0);
        acc2 = __builtin_amdgcn_mfma_f32_32x32x16_f16(al, bh[kt], acc2, 0, 0, 0);
      }
      {
        int off = hl ? 2048 : cc * 8;
        f16x8 aeh = *reinterpret_cast<const f16x8*>(&exh[off]);
        f16x8 ael = *reinterpret_cast<const f16x8*>(&exl[off]);
        acc = __builtin_amdgcn_mfma_f32_32x32x16_f16(aeh, beh, acc, 0, 0, 0);
        acc2 = __builtin_amdgcn_mfma_f32_32x32x16_f16(ael, beh, acc2, 0, 0, 0);
      }
#pragma unroll
      for (int r = 0; r < 16; ++r) {
        float dv = fmaf(acc2[r], LO_INV, acc[r]);
        int cr = mt * 32 + (r & 3) + 8 * (r >> 2) + 4 * hl;
        if (dv < bestd || (dv == bestd && cr < bestc)) { bestd = dv; bestc = cr; }
      }
    }

    float od = __shfl_xor(bestd, 32, 64);
    int oc = __shfl_xor(bestc, 32, 64);
    if (od < bestd || (od == bestd && oc < bestc)) { bestd = od; bestc = oc; }

    if (hl == 0) {
      out_idx[pt] = (float)bestc;
      out_iidx[pt] = bestc;
      atomicAdd(&hist[bestc], 1u);
    }
  }

  __syncthreads();
  if (tid < K) {
    unsigned int h = hist[tid];
    if (h) atomicAdd(&counts[tid], h);
  }
}

// ---------------- exclusive prefix of counts -> cursors ----------------
__global__ __launch_bounds__(256) void k_prefix(const unsigned int* __restrict__ counts,
                                                int* __restrict__ cursor) {
  __shared__ int tmp[257];
  int t = threadIdx.x;
  tmp[t + 1] = (int)counts[t];
  if (t == 0) tmp[0] = 0;
  __syncthreads();
  int x = tmp[t + 1];
  for (int off = 1; off < 256; off <<= 1) {
    int y = (t >= off) ? tmp[t + 1 - off] : 0;
    __syncthreads();
    x += y;
    tmp[t + 1] = x;
    __syncthreads();
  }
  cursor[t] = tmp[t];
}

// ---------------- counting-sort scatter ----------------
__global__ __launch_bounds__(1024) void k_scatter(const int* __restrict__ idx,
                                                  int* __restrict__ cursor,
                                                  int* __restrict__ sorted) {
  __shared__ int lh[K];
  __shared__ int lb[K];
  int t = threadIdx.x;
  int p = blockIdx.x * 1024 + t;
  int c = idx[p];
  if (t < K) lh[t] = 0;
  __syncthreads();
  atomicAdd(&lh[c], 1);
  __syncthreads();
  if (t < K) {
    int n = lh[t];
    lb[t] = n ? atomicAdd(&cursor[t], n) : 0;
    lh[t] = 0;
  }
  __syncthreads();
  int r = atomicAdd(&lh[c], 1);
  sorted[lb[c] + r] = (c << 22) | p;
}

// ---------------- fused K+V segment sum over the sorted list ----------------
// SP=32: 8192 groups; block-merged end-of-chunk flush (proven round 9).
constexpr int SP = 32;
__global__ __launch_bounds__(256) void k_psum2(const float* __restrict__ keys,
                                               const float* __restrict__ values,
                                               const int* __restrict__ sorted,
                                               float* __restrict__ ksum,
                                               float* __restrict__ vsum) {
  __shared__ float part[8][256];
  __shared__ int cid[8];

  const int sub = threadIdx.x & 31;
  const int lg = threadIdx.x >> 5;
  const int grp = blockIdx.x * 8 + lg;
  const int gbase = grp * SP;
  const int off = sub * 4;

  float4 ak = make_float4(0.f, 0.f, 0.f, 0.f);
  float4 av = make_float4(0.f, 0.f, 0.f, 0.f);
  int cur = sorted[gbase] >> 22;

#define FLUSH()                                            \
  {                                                        \
    float* fa = &ksum[(cur << 7) + off];                   \
    unsafeAtomicAdd(fa + 0, ak.x);                         \
    unsafeAtomicAdd(fa + 1, ak.y);                         \
    unsafeAtomicAdd(fa + 2, ak.z);                         \
    unsafeAtomicAdd(fa + 3, ak.w);                         \
    float* fb = &vsum[(cur << 7) + off];                   \
    unsafeAtomicAdd(fb + 0, av.x);                         \
    unsafeAtomicAdd(fb + 1, av.y);                         \
    unsafeAtomicAdd(fb + 2, av.z);                         \
    unsafeAtomicAdd(fb + 3, av.w);                         \
    ak = make_float4(0.f, 0.f, 0.f, 0.f);                  \
    av = make_float4(0.f, 0.f, 0.f, 0.f);                  \
  }

  for (int i = 0; i < SP; i += 4) {
    int4 e = *reinterpret_cast<const int4*>(&sorted[gbase + i]);
    size_t p0 = (size_t)(e.x & 0x3FFFFF) * D;
    size_t p1 = (size_t)(e.y & 0x3FFFFF) * D;
    size_t p2 = (size_t)(e.z & 0x3FFFFF) * D;
    size_t p3 = (size_t)(e.w & 0x3FFFFF) * D;
    float4 k0 = *reinterpret_cast<const float4*>(keys + p0 + off);
    float4 v0 = *reinterpret_cast<const float4*>(values + p0 + off);
    float4 k1 = *reinterpret_cast<const float4*>(keys + p1 + off);
    float4 v1 = *reinterpret_cast<const float4*>(values + p1 + off);
    float4 k2 = *reinterpret_cast<const float4*>(keys + p2 + off);
    float4 v2 = *reinterpret_cast<const float4*>(values + p2 + off);
    float4 k3 = *reinterpret_cast<const float4*>(keys + p3 + off);
    float4 v3 = *reinterpret_cast<const float4*>(values + p3 + off);
    int c0 = e.x >> 22, c1 = e.y >> 22, c2 = e.z >> 22, c3 = e.w >> 22;

    if (c0 != cur) { FLUSH(); cur = c0; }
    ak.x += k0.x; ak.y += k0.y; ak.z += k0.z; ak.w += k0.w;
    av.x += v0.x; av.y += v0.y; av.z += v0.z; av.w += v0.w;
    if (c1 != cur) { FLUSH(); cur = c1; }
    ak.x += k1.x; ak.y += k1.y; ak.z += k1.z; ak.w += k1.w;
    av.x += v1.x; av.y += v1.y; av.z += v1.z; av.w += v1.w;
    if (c2 != cur) { FLUSH(); cur = c2; }
    ak.x += k2.x; ak.y += k2.y; ak.z += k2.z; ak.w += k2.w;
    av.x += v2.x; av.y += v2.y; av.z += v2.z; av.w += v2.w;
    if (c3 != cur) { FLUSH(); cur = c3; }
    ak.x += k3.x; ak.y += k3.y; ak.z += k3.z; ak.w += k3.w;
    av.x += v3.x; av.y += v3.y; av.z += v3.z; av.w += v3.w;
  }
#undef FLUSH

  *reinterpret_cast<float4*>(&part[lg][off]) = ak;
  *reinterpret_cast<float4*>(&part[lg][128 + off]) = av;
  if (sub == 0) cid[lg] = cur;
  __syncthreads();

  int c = cid[lg];
  bool owner = (lg == 0) || (cid[lg - 1] != c);
  if (owner) {
    float4 sk = make_float4(0.f, 0.f, 0.f, 0.f);
    float4 sv = make_float4(0.f, 0.f, 0.f, 0.f);
    for (int s = lg; s < 8 && cid[s] == c; ++s) {
      float4 pk = *reinterpret_cast<const float4*>(&part[s][off]);
      float4 pv = *reinterpret_cast<const float4*>(&part[s][128 + off]);
      sk.x += pk.x; sk.y += pk.y; sk.z += pk.z; sk.w += pk.w;
      sv.x += pv.x; sv.y += pv.y; sv.z += pv.z; sv.w += pv.w;
    }
    float* fa = &ksum[(c << 7) + off];
    unsafeAtomicAdd(fa + 0, sk.x);
    unsafeAtomicAdd(fa + 1, sk.y);
    unsafeAtomicAdd(fa + 2, sk.z);
    unsafeAtomicAdd(fa + 3, sk.w);
    float* fb = &vsum[(c << 7) + off];
    unsafeAtomicAdd(fb + 0, sv.x);
    unsafeAtomicAdd(fb + 1, sv.y);
    unsafeAtomicAdd(fb + 2, sv.z);
    unsafeAtomicAdd(fb + 3, sv.w);
  }
}

// ---------------- fallback psum (float idx) ----------------
__global__ __launch_bounds__(1024) void k_psum_fb(const float* __restrict__ src,
                                                  const float* __restrict__ idxf,
                                                  float* __restrict__ gacc, int ppb) {
  __shared__ float acc[K * D];
  for (int i = threadIdx.x; i < K * D; i += 1024) acc[i] = 0.f;
  __syncthreads();
  const int d = threadIdx.x & 127;
  const int ps = threadIdx.x >> 7;
  const int base = blockIdx.x * ppb;
#pragma unroll 4
  for (int p = ps; p < ppb; p += 8) {
    int c = (int)idxf[base + p];
    float v = src[(size_t)(base + p) * D + d];
    unsafeAtomicAdd(&acc[(c << 7) + d], v);
  }
  __syncthreads();
  for (int i = threadIdx.x; i < K * D; i += 1024) {
    float v = acc[i];
    if (v != 0.f) unsafeAtomicAdd(&gacc[i], v);
  }
}

// ---------------- EMA update + counts ----------------
__global__ __launch_bounds__(256) void k_finish(
    const float* __restrict__ ksum, const float* __restrict__ vsum,
    const float* __restrict__ kc, const float* __restrict__ vc,
    const float* __restrict__ oldcnt, const unsigned int* __restrict__ counts,
    float* __restrict__ ok, float* __restrict__ ov, float* __restrict__ ocnt) {
  int i = blockIdx.x * 256 + threadIdx.x;
  int c = i >> 7;
  float cnt = (float)counts[c];
  float safe = fmaxf(cnt, 1.0f);
  float km = ksum[i] / safe, vm = vsum[i] / safe;
  float okc = kc[i], ovc = vc[i];
  bool ne = cnt > 0.f;
  ok[i] = ne ? (1.0f - LR) * okc + LR * km : okc;
  ov[i] = ne ? (1.0f - LR) * ovc + LR * vm : ovc;
  if ((i & 127) == 0) ocnt[c] = oldcnt[c] + cnt;
}

extern "C" void kernel_launch(void* const* d_in, const int* in_sizes, int n_in,
                              void* d_out, int out_size, void* d_ws, size_t ws_size,
                              hipStream_t stream) {
  const float* keys = (const float*)d_in[0];
  const float* values = (const float*)d_in[1];
  const float* kcent = (const float*)d_in[2];
  const float* vcent = (const float*)d_in[3];
  const float* oldcnt = (const float*)d_in[4];
  const int N = in_sizes[0] / D;  // 262144

  float* ws = (float*)d_ws;
  unsigned int* w_counts = (unsigned int*)ws;          // 0      .. 256
  float* w_ksum = ws + 256;                            // 256    .. 33024
  float* w_vsum = ws + 33024;                          // 33024  .. 65792
  _Float16* w_csplit = (_Float16*)(ws + 65792);        // 65792  .. 98560
  _Float16* w_extH = w_csplit + 65536;                 // 98560  .. 99584
  _Float16* w_extL = w_extH + 2048;                    // 99584  .. 100608
  int* w_idx = (int*)(ws + 100608);                    // 100608 .. 362752
  int* w_cursor = (int*)(ws + 100608 + N);             // 362752 .. 363008
  int* w_sorted = (int*)(ws + 363008);                 // 363008 .. 363008+N

  float* o_idx = (float*)d_out;  // N
  float* o_kc = o_idx + N;       // K*D
  float* o_vc = o_kc + K * D;    // K*D
  float* o_cnt = o_vc + K * D;   // K

  size_t need_sorted = (size_t)(363008 + N) * 4;
  bool sorted_path = ws_size >= need_sorted;

  int zn = 256 + 2 * K * D;  // counts + ksum + vsum
  k_zero<<<(zn + 255) / 256, 256, 0, stream>>>(ws, zn);
  k_prep<<<K, 128, 0, stream>>>(kcent, w_csplit, w_extH, w_extL);

  const int T = 2;  // 512-pt tiles per block -> grid 256 = 1 block/CU, one round
  k_assign<<<N / (512 * T), 1024, 0, stream>>>(keys, w_csplit, w_extH, w_extL, o_idx,
                                               sorted_path ? w_idx : w_cursor,
                                               w_counts, T);
  if (sorted_path) {
    k_prefix<<<1, 256, 0, stream>>>(w_counts, w_cursor);
    k_scatter<<<N / 1024, 1024, 0, stream>>>(w_idx, w_cursor, w_sorted);
    k_psum2<<<N / (SP * 8), 256, 0, stream>>>(keys, values, w_sorted, w_ksum, w_vsum);
  } else {
    int ppb = N / 256;
    k_psum_fb<<<256, 1024, 0, stream>>>(keys, o_idx, w_ksum, ppb);
    k_psum_fb<<<256, 1024, 0, stream>>>(values, o_idx, w_vsum, ppb);
  }
  k_finish<<<(K * D) / 256, 256, 0, stream>>>(w_ksum, w_vsum, kcent, vcent, oldcnt,
                                              w_counts, o_kc, o_vc, o_cnt);
}